// Round 4
// baseline (191.772 us; speedup 1.0000x reference)
//
#include <hip/hip_runtime.h>
#include <stdint.h>

// ---------------------------------------------------------------------------
// CrossAttention_43061342110469 — algebraic reduction:
// einsum('bvhd,bhqk->bvhd', v, softmax(scores)) == v * L  (softmax rows sum
// to 1; summed over q gives L=2048). So out = 2048*(x @ Wv @ Wo) + const.
// encoder_x / Wq / bq / Wk / bk do not affect the output.
//
// 4 kernels: transpose_cast(Wo), bias_fuse, gemm_w (Wt=2048*(Wv@Wo)^T, fp32
// Wv staged + converted in-register), gemm_main (out = x@Wt^T + bias, fp32 x
// staged + converted in-register). No standalone cast passes, no split-K.
// ---------------------------------------------------------------------------

typedef __attribute__((ext_vector_type(8))) short bf16x8;
typedef __attribute__((ext_vector_type(4))) float f32x4;

typedef __attribute__((address_space(1))) void as1_void;
typedef __attribute__((address_space(3))) void as3_void;
#define GLD16(g, s)                                                          \
  __builtin_amdgcn_global_load_lds((as1_void*)(g), (as3_void*)(s), 16, 0, 0)

__device__ __forceinline__ short f2bf(float f) {
  union { float f; uint32_t u; } v; v.f = f;
  uint32_t r = v.u + 0x7FFFu + ((v.u >> 16) & 1u);  // round-to-nearest-even
  return (short)(r >> 16);
}

// pack 8 fp32 -> bf16x8 with round-half-up (+0x8000 then take high16 via
// v_perm). Error ~= RNE; 12 VALU ops total, hidden under MFMA pipe.
__device__ __forceinline__ bf16x8 pack8(f32x4 a, f32x4 b) {
  union { f32x4 f; uint32_t u[4]; } x, y;
  x.f = a; y.f = b;
#pragma unroll
  for (int t = 0; t < 4; ++t) x.u[t] += 0x8000u;
#pragma unroll
  for (int t = 0; t < 4; ++t) y.u[t] += 0x8000u;
  union { bf16x8 v; uint32_t u[4]; } o;
  o.u[0] = __builtin_amdgcn_perm(x.u[1], x.u[0], 0x07060302);
  o.u[1] = __builtin_amdgcn_perm(x.u[3], x.u[2], 0x07060302);
  o.u[2] = __builtin_amdgcn_perm(y.u[1], y.u[0], 0x07060302);
  o.u[3] = __builtin_amdgcn_perm(y.u[3], y.u[2], 0x07060302);
  return o.v;
}

// ---- 1024x1024 fp32 -> bf16 transpose-cast (64x64 tiles via LDS) -----------
__global__ __launch_bounds__(256) void transpose_cast(
    const float* __restrict__ in, short* __restrict__ out, int n) {
  __shared__ float tile[64][65];
  const int br = blockIdx.y * 64, bc = blockIdx.x * 64;
  const int tid = threadIdx.x;
#pragma unroll
  for (int t = 0; t < 16; ++t) {
    int idx = t * 256 + tid;
    int r = idx >> 6, c = idx & 63;
    tile[r][c] = in[(size_t)(br + r) * n + bc + c];
  }
  __syncthreads();
#pragma unroll
  for (int t = 0; t < 16; ++t) {
    int idx = t * 256 + tid;
    int r = idx >> 6, c = idx & 63;
    out[(size_t)(bc + r) * n + br + c] = f2bf(tile[c][r]);
  }
}

// ---- bias_c[n] = 2048 * sum_k bv[k]*Wo[k,n] + bo[n] ------------------------
__global__ __launch_bounds__(256) void bias_fuse(
    const float* __restrict__ bv, const float* __restrict__ Wo,
    const float* __restrict__ bo, float* __restrict__ biasc, int D, int N) {
  __shared__ float red[256];
  const int tid = threadIdx.x;
  const int nx = tid & 15, ky = tid >> 4;
  const int n = blockIdx.x * 16 + nx;
  float s = 0.f;
  for (int k = ky; k < D; k += 16)
    s += bv[k] * Wo[(size_t)k * N + n];
  red[tid] = s;
  __syncthreads();
#pragma unroll
  for (int st = 128; st >= 16; st >>= 1) {
    if (tid < st) red[tid] += red[tid + st];
    __syncthreads();
  }
  if (ky == 0) biasc[n] = 2048.0f * red[nx] + bo[n];
}

// ---- Wt[m,k'] = 2048 * sum_j Wot[m,j] * Wv[k',j]; Wv staged as fp32 --------
// BM=BN=64, BK=64, grid 16x16 (256 blocks = full chip), 4 waves each 32x32.
// XOR chunk swizzle on both tiles (2-way bank alias only = free, m136).
__global__ __launch_bounds__(256) void gemm_w(
    const short* __restrict__ Wot, const float* __restrict__ Wv,
    short* __restrict__ Wt, int N, int K) {
  constexpr int BK = 64;
  __shared__ __align__(16) short As[64 * BK];   //  8 KB bf16
  __shared__ __align__(16) float Bsf[64 * BK];  // 16 KB fp32
  const int tid = threadIdx.x, lane = tid & 63, wave = tid >> 6;
  const int bm = blockIdx.y * 64, bn = blockIdx.x * 64;
  const int wm = (wave >> 1) * 32, wn = (wave & 1) * 32;
  const int l15 = lane & 15, quad = lane >> 4;

  f32x4 acc[2][2];
#pragma unroll
  for (int i = 0; i < 2; ++i)
#pragma unroll
    for (int j = 0; j < 2; ++j) acc[i][j] = (f32x4){0.f, 0.f, 0.f, 0.f};

  // A (bf16): 64 rows x 8 chunks(16B); thread rows tid>>3 (+32), c8s=tid&7
  const int ar = tid >> 3, ac8 = (tid & 7) ^ (ar & 7);
  const short* pa = Wot + (size_t)(bm + ar) * K + ac8 * 8;
  short* la = As + tid * 8;
  // B (fp32): 64 rows x 16 chunks(16B); thread rows tid>>4 (+16*s), c4s=tid&15
  const int br = tid >> 4, bc4 = (tid & 15) ^ (br & 7);
  const float* pb = Wv + (size_t)(bn + br) * K + bc4 * 4;
  float* lb = Bsf + tid * 4;

  for (int kt = 0; kt < K; kt += BK) {
#pragma unroll
    for (int s = 0; s < 2; ++s) GLD16(pa + (size_t)(32 * s) * K, la + 2048 * s);
#pragma unroll
    for (int s = 0; s < 4; ++s) GLD16(pb + (size_t)(16 * s) * K, lb + 1024 * s);
    pa += BK; pb += BK;
    __syncthreads();
#pragma unroll
    for (int kk = 0; kk < 2; ++kk) {
      bf16x8 af[2], bfr[2];
#pragma unroll
      for (int i = 0; i < 2; ++i) {
        const int r = wm + i * 16 + l15;
        af[i] = *(const bf16x8*)(As + r * BK + ((kk * 4 + quad) ^ (r & 7)) * 8);
      }
#pragma unroll
      for (int j = 0; j < 2; ++j) {
        const int r = wn + j * 16 + l15;
        const int c4 = kk * 8 + quad * 2;
        f32x4 u0 = *(const f32x4*)(Bsf + (r * 16 + (c4 ^ (r & 7))) * 4);
        f32x4 u1 = *(const f32x4*)(Bsf + (r * 16 + ((c4 + 1) ^ (r & 7))) * 4);
        bfr[j] = pack8(u0, u1);
      }
#pragma unroll
      for (int i = 0; i < 2; ++i)
#pragma unroll
        for (int j = 0; j < 2; ++j)
          acc[i][j] = __builtin_amdgcn_mfma_f32_16x16x32_bf16(
              af[i], bfr[j], acc[i][j], 0, 0, 0);
    }
    __syncthreads();
  }
#pragma unroll
  for (int j = 0; j < 2; ++j) {
    const int col = bn + wn + j * 16 + l15;
#pragma unroll
    for (int i = 0; i < 2; ++i) {
      const int row0 = bm + wm + i * 16 + quad * 4;
#pragma unroll
      for (int r = 0; r < 4; ++r)
        Wt[(size_t)(row0 + r) * N + col] = f2bf(2048.f * acc[i][j][r]);
    }
  }
}

// ---- out = x @ Wt^T + bias; x staged as fp32, converted in-register --------
// BM=BN=128, BK=64, 256 thr (4 waves x 64x64), grid 8x64 = 512 blocks.
// LDS 48 KB (A fp32 32 KB + B bf16 16 KB).
__global__ __launch_bounds__(256) void gemm_main(
    const float* __restrict__ X, const short* __restrict__ Wt,
    const float* __restrict__ bias, float* __restrict__ Out,
    int M, int N, int K) {
  constexpr int BK = 64;
  __shared__ __align__(16) float Asf[128 * BK];  // 32 KB fp32
  __shared__ __align__(16) short Bs[128 * BK];   // 16 KB bf16
  const int tid = threadIdx.x, lane = tid & 63, wave = tid >> 6;
  const int bm = blockIdx.y * 128, bn = blockIdx.x * 128;
  const int wm = (wave >> 1) * 64, wn = (wave & 1) * 64;
  const int l15 = lane & 15, quad = lane >> 4;

  f32x4 acc[4][4];
#pragma unroll
  for (int i = 0; i < 4; ++i)
#pragma unroll
    for (int j = 0; j < 4; ++j) acc[i][j] = (f32x4){0.f, 0.f, 0.f, 0.f};

  // A (fp32): 128 rows x 16 chunks(16B); thread rows tid>>4 (+16*s), c4s=tid&15
  const int ar = tid >> 4, ac4 = (tid & 15) ^ (ar & 7);
  const float* pa = X + (size_t)(bm + ar) * K + ac4 * 4;
  float* la = Asf + tid * 4;
  // B (bf16): 128 rows x 8 chunks(16B); thread rows tid>>3 (+32*s), c8s=tid&7
  const int br = tid >> 3, bc8 = (tid & 7) ^ (br & 7);
  const short* pb = Wt + (size_t)(bn + br) * K + bc8 * 8;
  short* lb = Bs + tid * 8;

  for (int kt = 0; kt < K; kt += BK) {
#pragma unroll
    for (int s = 0; s < 8; ++s) GLD16(pa + (size_t)(16 * s) * K, la + 1024 * s);
#pragma unroll
    for (int s = 0; s < 4; ++s) GLD16(pb + (size_t)(32 * s) * K, lb + 2048 * s);
    pa += BK; pb += BK;
    __syncthreads();
#pragma unroll
    for (int kk = 0; kk < 2; ++kk) {
      bf16x8 af[4], bfr[4];
#pragma unroll
      for (int i = 0; i < 4; ++i) {
        const int r = wm + i * 16 + l15;
        const int c4 = kk * 8 + quad * 2;
        f32x4 u0 = *(const f32x4*)(Asf + (r * 16 + (c4 ^ (r & 7))) * 4);
        f32x4 u1 = *(const f32x4*)(Asf + (r * 16 + ((c4 + 1) ^ (r & 7))) * 4);
        af[i] = pack8(u0, u1);
      }
#pragma unroll
      for (int j = 0; j < 4; ++j) {
        const int r = wn + j * 16 + l15;
        bfr[j] = *(const bf16x8*)(Bs + r * BK + ((kk * 4 + quad) ^ (r & 7)) * 8);
      }
#pragma unroll
      for (int i = 0; i < 4; ++i)
#pragma unroll
        for (int j = 0; j < 4; ++j)
          acc[i][j] = __builtin_amdgcn_mfma_f32_16x16x32_bf16(
              af[i], bfr[j], acc[i][j], 0, 0, 0);
    }
    __syncthreads();
  }

  // epilogue: C/D layout col=lane&15, row=(lane>>4)*4+reg (verified m89/m91)
#pragma unroll
  for (int j = 0; j < 4; ++j) {
    const int col = bn + wn + j * 16 + l15;
    const float bb = bias[col];
#pragma unroll
    for (int i = 0; i < 4; ++i) {
      const int row0 = bm + wm + i * 16 + quad * 4;
#pragma unroll
      for (int r = 0; r < 4; ++r)
        Out[(size_t)(row0 + r) * N + col] = acc[i][j][r] + bb;
    }
  }
}

extern "C" void kernel_launch(void* const* d_in, const int* in_sizes, int n_in,
                              void* d_out, int out_size, void* d_ws,
                              size_t ws_size, hipStream_t stream) {
  // setup_inputs order: x, encoder_x, Wq, bq, Wk, bk, Wv, bv, Wo, bo
  const float* x  = (const float*)d_in[0];
  const float* Wv = (const float*)d_in[6];
  const float* bv = (const float*)d_in[7];
  const float* Wo = (const float*)d_in[8];
  const float* bo = (const float*)d_in[9];
  float* out = (float*)d_out;

  constexpr int L = 2048, D = 1024, NO = 1024;  // NO = H*QKV
  constexpr int M = 4 * L;                      // B*L = 8192

  char* ws = (char*)d_ws;
  short* wot_bf = (short*)(ws);                 // 2 MB: Wo^T bf16
  short* wt_bf  = (short*)(ws + (2u << 20));    // 2 MB: 2048*(Wv@Wo)^T bf16
  float* biasc  = (float*)(ws + (4u << 20));    // 4 KB: fused bias

  transpose_cast<<<dim3(16, 16), 256, 0, stream>>>(Wo, wot_bf, NO);
  bias_fuse<<<NO / 16, 256, 0, stream>>>(bv, Wo, bo, biasc, D, NO);
  gemm_w<<<dim3(16, 16), 256, 0, stream>>>(wot_bf, Wv, wt_bf, NO, D);
  gemm_main<<<dim3(NO / 128, M / 128), 256, 0, stream>>>(
      x, wt_bf, biasc, out, M, NO, D);
}

// Round 5
// 190.545 us; speedup vs baseline: 1.0064x; 1.0064x over previous
//
#include <hip/hip_runtime.h>
#include <stdint.h>

// ---------------------------------------------------------------------------
// CrossAttention_43061342110469 — algebraic reduction:
// einsum('bvhd,bhqk->bvhd', v, softmax(scores)) == v * L  (softmax rows sum
// to 1; summed over q gives L=2048). So out = 2048*(x @ Wv @ Wo) + const.
// encoder_x / Wq / bq / Wk / bk do not affect the output.
//
// 5 kernels: cast_x (fp32->bf16; keeps the 8x-reread operand bf16 so L2/L3
// absorb it — R4's fp32-staging fused variant hit 132 MB HBM fetch),
// transpose_cast(Wo), bias_fuse, gemm_w (Wt = 2048*(Wv@Wo)^T, fp32 Wv staged,
// in-register convert — fine at this tiny size), gemm_main (bf16 x bf16).
// ---------------------------------------------------------------------------

typedef __attribute__((ext_vector_type(8))) short bf16x8;
typedef __attribute__((ext_vector_type(4))) float f32x4;

typedef __attribute__((address_space(1))) void as1_void;
typedef __attribute__((address_space(3))) void as3_void;
#define GLD16(g, s)                                                          \
  __builtin_amdgcn_global_load_lds((as1_void*)(g), (as3_void*)(s), 16, 0, 0)

__device__ __forceinline__ short f2bf(float f) {
  union { float f; uint32_t u; } v; v.f = f;
  uint32_t r = v.u + 0x7FFFu + ((v.u >> 16) & 1u);  // round-to-nearest-even
  return (short)(r >> 16);
}

// pack 8 fp32 -> bf16x8, round-half-up (+0x8000, take high16 via v_perm)
__device__ __forceinline__ bf16x8 pack8(f32x4 a, f32x4 b) {
  union { f32x4 f; uint32_t u[4]; } x, y;
  x.f = a; y.f = b;
#pragma unroll
  for (int t = 0; t < 4; ++t) x.u[t] += 0x8000u;
#pragma unroll
  for (int t = 0; t < 4; ++t) y.u[t] += 0x8000u;
  union { bf16x8 v; uint32_t u[4]; } o;
  o.u[0] = __builtin_amdgcn_perm(x.u[1], x.u[0], 0x07060302);
  o.u[1] = __builtin_amdgcn_perm(x.u[3], x.u[2], 0x07060302);
  o.u[2] = __builtin_amdgcn_perm(y.u[1], y.u[0], 0x07060302);
  o.u[3] = __builtin_amdgcn_perm(y.u[3], y.u[2], 0x07060302);
  return o.v;
}

// ---- fp32 -> bf16 cast, 8 elems/thread, fully vectorized -------------------
__global__ __launch_bounds__(256) void cast_f32_bf16(
    const float* __restrict__ in, short* __restrict__ out, int n8) {
  int i = blockIdx.x * blockDim.x + threadIdx.x;
  if (i >= n8) return;
  const float4* p = (const float4*)in;
  float4 a = p[2 * (size_t)i], b = p[2 * (size_t)i + 1];
  bf16x8 o;
  o[0] = f2bf(a.x); o[1] = f2bf(a.y); o[2] = f2bf(a.z); o[3] = f2bf(a.w);
  o[4] = f2bf(b.x); o[5] = f2bf(b.y); o[6] = f2bf(b.z); o[7] = f2bf(b.w);
  *(bf16x8*)(out + 8 * (size_t)i) = o;
}

// ---- 1024x1024 fp32 -> bf16 transpose-cast (64x64 tiles via LDS) -----------
__global__ __launch_bounds__(256) void transpose_cast(
    const float* __restrict__ in, short* __restrict__ out, int n) {
  __shared__ float tile[64][65];
  const int br = blockIdx.y * 64, bc = blockIdx.x * 64;
  const int tid = threadIdx.x;
#pragma unroll
  for (int t = 0; t < 16; ++t) {
    int idx = t * 256 + tid;
    int r = idx >> 6, c = idx & 63;
    tile[r][c] = in[(size_t)(br + r) * n + bc + c];
  }
  __syncthreads();
#pragma unroll
  for (int t = 0; t < 16; ++t) {
    int idx = t * 256 + tid;
    int r = idx >> 6, c = idx & 63;
    out[(size_t)(bc + r) * n + br + c] = f2bf(tile[c][r]);
  }
}

// ---- bias_c[n] = 2048 * sum_k bv[k]*Wo[k,n] + bo[n] ------------------------
__global__ __launch_bounds__(256) void bias_fuse(
    const float* __restrict__ bv, const float* __restrict__ Wo,
    const float* __restrict__ bo, float* __restrict__ biasc, int D, int N) {
  __shared__ float red[256];
  const int tid = threadIdx.x;
  const int nx = tid & 15, ky = tid >> 4;
  const int n = blockIdx.x * 16 + nx;
  float s = 0.f;
  for (int k = ky; k < D; k += 16)
    s += bv[k] * Wo[(size_t)k * N + n];
  red[tid] = s;
  __syncthreads();
#pragma unroll
  for (int st = 128; st >= 16; st >>= 1) {
    if (tid < st) red[tid] += red[tid + st];
    __syncthreads();
  }
  if (ky == 0) biasc[n] = 2048.0f * red[nx] + bo[n];
}

// ---- Wt[m,k'] = 2048 * sum_j Wot[m,j] * Wv[k',j]; Wv staged as fp32 --------
// BM=BN=64, BK=64, grid 16x16 (256 blocks = full chip), 4 waves each 32x32.
__global__ __launch_bounds__(256) void gemm_w(
    const short* __restrict__ Wot, const float* __restrict__ Wv,
    short* __restrict__ Wt, int N, int K) {
  constexpr int BK = 64;
  __shared__ __align__(16) short As[64 * BK];   //  8 KB bf16
  __shared__ __align__(16) float Bsf[64 * BK];  // 16 KB fp32
  const int tid = threadIdx.x, lane = tid & 63, wave = tid >> 6;
  const int bm = blockIdx.y * 64, bn = blockIdx.x * 64;
  const int wm = (wave >> 1) * 32, wn = (wave & 1) * 32;
  const int l15 = lane & 15, quad = lane >> 4;

  f32x4 acc[2][2];
#pragma unroll
  for (int i = 0; i < 2; ++i)
#pragma unroll
    for (int j = 0; j < 2; ++j) acc[i][j] = (f32x4){0.f, 0.f, 0.f, 0.f};

  const int ar = tid >> 3, ac8 = (tid & 7) ^ (ar & 7);
  const short* pa = Wot + (size_t)(bm + ar) * K + ac8 * 8;
  short* la = As + tid * 8;
  const int br = tid >> 4, bc4 = (tid & 15) ^ (br & 7);
  const float* pb = Wv + (size_t)(bn + br) * K + bc4 * 4;
  float* lb = Bsf + tid * 4;

  for (int kt = 0; kt < K; kt += BK) {
#pragma unroll
    for (int s = 0; s < 2; ++s) GLD16(pa + (size_t)(32 * s) * K, la + 2048 * s);
#pragma unroll
    for (int s = 0; s < 4; ++s) GLD16(pb + (size_t)(16 * s) * K, lb + 1024 * s);
    pa += BK; pb += BK;
    __syncthreads();
#pragma unroll
    for (int kk = 0; kk < 2; ++kk) {
      bf16x8 af[2], bfr[2];
#pragma unroll
      for (int i = 0; i < 2; ++i) {
        const int r = wm + i * 16 + l15;
        af[i] = *(const bf16x8*)(As + r * BK + ((kk * 4 + quad) ^ (r & 7)) * 8);
      }
#pragma unroll
      for (int j = 0; j < 2; ++j) {
        const int r = wn + j * 16 + l15;
        const int c4 = kk * 8 + quad * 2;
        f32x4 u0 = *(const f32x4*)(Bsf + (r * 16 + (c4 ^ (r & 7))) * 4);
        f32x4 u1 = *(const f32x4*)(Bsf + (r * 16 + ((c4 + 1) ^ (r & 7))) * 4);
        bfr[j] = pack8(u0, u1);
      }
#pragma unroll
      for (int i = 0; i < 2; ++i)
#pragma unroll
        for (int j = 0; j < 2; ++j)
          acc[i][j] = __builtin_amdgcn_mfma_f32_16x16x32_bf16(
              af[i], bfr[j], acc[i][j], 0, 0, 0);
    }
    __syncthreads();
  }
#pragma unroll
  for (int j = 0; j < 2; ++j) {
    const int col = bn + wn + j * 16 + l15;
#pragma unroll
    for (int i = 0; i < 2; ++i) {
      const int row0 = bm + wm + i * 16 + quad * 4;
#pragma unroll
      for (int r = 0; r < 4; ++r)
        Wt[(size_t)(row0 + r) * N + col] = f2bf(2048.f * acc[i][j][r]);
    }
  }
}

// ---- out = x_bf @ Wt^T + bias; pure bf16 LDS K-loop (R3-proven) ------------
// BM=BN=128, BK=64, 256 thr (4 waves x 64x64 as 4x4 of 16x16x32 MFMA).
// XOR chunk swizzle: LDS[row][c8] = global chunk [row][c8^(row&7)] -> frag
// ds_read_b128 spread over all 32 banks (2-way alias only = free).
__global__ __launch_bounds__(256) void gemm_main(
    const short* __restrict__ A, const short* __restrict__ Bt,
    const float* __restrict__ bias, float* __restrict__ Out,
    int M, int N, int K) {
  constexpr int BK = 64;
  __shared__ __align__(16) short As[128 * BK];  // 16 KB
  __shared__ __align__(16) short Bs[128 * BK];  // 16 KB
  const int tid = threadIdx.x, lane = tid & 63, wave = tid >> 6;
  const int bm = blockIdx.y * 128, bn = blockIdx.x * 128;
  const int wm = (wave >> 1) * 64, wn = (wave & 1) * 64;
  const int l15 = lane & 15, quad = lane >> 4;

  f32x4 acc[4][4];
#pragma unroll
  for (int i = 0; i < 4; ++i)
#pragma unroll
    for (int j = 0; j < 4; ++j) acc[i][j] = (f32x4){0.f, 0.f, 0.f, 0.f};

  const int srow = tid >> 3, sc8 = (tid & 7) ^ (srow & 7);
  const short* pa = A + (size_t)(bm + srow) * K + sc8 * 8;
  const short* pb = Bt + (size_t)(bn + srow) * K + sc8 * 8;
  short* la = As + tid * 8;
  short* lb = Bs + tid * 8;

  for (int kt = 0; kt < K; kt += BK) {
#pragma unroll
    for (int s = 0; s < 4; ++s) {
      GLD16(pa + (size_t)(32 * s) * K, la + 2048 * s);
      GLD16(pb + (size_t)(32 * s) * K, lb + 2048 * s);
    }
    pa += BK; pb += BK;
    __syncthreads();
#pragma unroll
    for (int kk = 0; kk < 2; ++kk) {
      bf16x8 af[4], bfr[4];
#pragma unroll
      for (int i = 0; i < 4; ++i) {
        const int r = wm + i * 16 + l15;
        af[i] = *(const bf16x8*)(As + r * BK + ((kk * 4 + quad) ^ (r & 7)) * 8);
      }
#pragma unroll
      for (int j = 0; j < 4; ++j) {
        const int r = wn + j * 16 + l15;
        bfr[j] = *(const bf16x8*)(Bs + r * BK + ((kk * 4 + quad) ^ (r & 7)) * 8);
      }
#pragma unroll
      for (int i = 0; i < 4; ++i)
#pragma unroll
        for (int j = 0; j < 4; ++j)
          acc[i][j] = __builtin_amdgcn_mfma_f32_16x16x32_bf16(
              af[i], bfr[j], acc[i][j], 0, 0, 0);
    }
    __syncthreads();
  }

  // epilogue: C/D layout col=lane&15, row=(lane>>4)*4+reg (verified m89/m91)
#pragma unroll
  for (int j = 0; j < 4; ++j) {
    const int col = bn + wn + j * 16 + l15;
    const float bb = bias[col];
#pragma unroll
    for (int i = 0; i < 4; ++i) {
      const int row0 = bm + wm + i * 16 + quad * 4;
#pragma unroll
      for (int r = 0; r < 4; ++r)
        Out[(size_t)(row0 + r) * N + col] = acc[i][j][r] + bb;
    }
  }
}

extern "C" void kernel_launch(void* const* d_in, const int* in_sizes, int n_in,
                              void* d_out, int out_size, void* d_ws,
                              size_t ws_size, hipStream_t stream) {
  // setup_inputs order: x, encoder_x, Wq, bq, Wk, bk, Wv, bv, Wo, bo
  const float* x  = (const float*)d_in[0];
  const float* Wv = (const float*)d_in[6];
  const float* bv = (const float*)d_in[7];
  const float* Wo = (const float*)d_in[8];
  const float* bo = (const float*)d_in[9];
  float* out = (float*)d_out;

  constexpr int L = 2048, D = 1024, NO = 1024;  // NO = H*QKV
  constexpr int M = 4 * L;                      // B*L = 8192

  char* ws = (char*)d_ws;
  short* x_bf   = (short*)(ws);                 // 16 MB: x as bf16
  short* wot_bf = (short*)(ws + (16u << 20));   //  2 MB: Wo^T bf16
  short* wt_bf  = (short*)(ws + (18u << 20));   //  2 MB: 2048*(Wv@Wo)^T bf16
  float* biasc  = (float*)(ws + (20u << 20));   //  4 KB: fused bias

  cast_f32_bf16<<<(M * D / 8) / 256, 256, 0, stream>>>(x, x_bf, M * D / 8);
  transpose_cast<<<dim3(16, 16), 256, 0, stream>>>(Wo, wot_bf, NO);
  bias_fuse<<<NO / 16, 256, 0, stream>>>(bv, Wo, bo, biasc, D, NO);
  gemm_w<<<dim3(16, 16), 256, 0, stream>>>(wot_bf, Wv, wt_bf, NO, D);
  gemm_main<<<dim3(NO / 128, M / 128), 256, 0, stream>>>(
      x_bf, wt_bf, biasc, out, M, NO, D);
}

// Round 6
// 185.166 us; speedup vs baseline: 1.0357x; 1.0290x over previous
//
#include <hip/hip_runtime.h>
#include <stdint.h>

// ---------------------------------------------------------------------------
// CrossAttention_43061342110469 — algebraic reduction:
// einsum('bvhd,bhqk->bvhd', v, softmax(scores)) == v * L  (softmax rows sum
// to 1; summed over q gives L=2048). So out = 2048*(x @ Wv @ Wo) + const.
// encoder_x / Wq / bq / Wk / bk do not affect the output.
//
// 5 kernels: cast_x, transpose_cast(Wo), bias_fuse, gemm_w, gemm_main.
// gemm_main R6: 128x64 tiles (1024 blocks = 4/CU for latency hiding),
// XCD-aware block order (blocks sharing an A-tile share an XCD's L2),
// LDS-transposed coalesced epilogue (full-line dwordx4 stores).
// ---------------------------------------------------------------------------

typedef __attribute__((ext_vector_type(8))) short bf16x8;
typedef __attribute__((ext_vector_type(4))) float f32x4;

typedef __attribute__((address_space(1))) void as1_void;
typedef __attribute__((address_space(3))) void as3_void;
#define GLD16(g, s)                                                          \
  __builtin_amdgcn_global_load_lds((as1_void*)(g), (as3_void*)(s), 16, 0, 0)

__device__ __forceinline__ short f2bf(float f) {
  union { float f; uint32_t u; } v; v.f = f;
  uint32_t r = v.u + 0x7FFFu + ((v.u >> 16) & 1u);  // round-to-nearest-even
  return (short)(r >> 16);
}

// pack 8 fp32 -> bf16x8, round-half-up (+0x8000, take high16 via v_perm)
__device__ __forceinline__ bf16x8 pack8(f32x4 a, f32x4 b) {
  union { f32x4 f; uint32_t u[4]; } x, y;
  x.f = a; y.f = b;
#pragma unroll
  for (int t = 0; t < 4; ++t) x.u[t] += 0x8000u;
#pragma unroll
  for (int t = 0; t < 4; ++t) y.u[t] += 0x8000u;
  union { bf16x8 v; uint32_t u[4]; } o;
  o.u[0] = __builtin_amdgcn_perm(x.u[1], x.u[0], 0x07060302);
  o.u[1] = __builtin_amdgcn_perm(x.u[3], x.u[2], 0x07060302);
  o.u[2] = __builtin_amdgcn_perm(y.u[1], y.u[0], 0x07060302);
  o.u[3] = __builtin_amdgcn_perm(y.u[3], y.u[2], 0x07060302);
  return o.v;
}

// ---- fp32 -> bf16 cast, 8 elems/thread, fully vectorized -------------------
__global__ __launch_bounds__(256) void cast_f32_bf16(
    const float* __restrict__ in, short* __restrict__ out, int n8) {
  int i = blockIdx.x * blockDim.x + threadIdx.x;
  if (i >= n8) return;
  const float4* p = (const float4*)in;
  float4 a = p[2 * (size_t)i], b = p[2 * (size_t)i + 1];
  bf16x8 o;
  o[0] = f2bf(a.x); o[1] = f2bf(a.y); o[2] = f2bf(a.z); o[3] = f2bf(a.w);
  o[4] = f2bf(b.x); o[5] = f2bf(b.y); o[6] = f2bf(b.z); o[7] = f2bf(b.w);
  *(bf16x8*)(out + 8 * (size_t)i) = o;
}

// ---- 1024x1024 fp32 -> bf16 transpose-cast (64x64 tiles via LDS) -----------
__global__ __launch_bounds__(256) void transpose_cast(
    const float* __restrict__ in, short* __restrict__ out, int n) {
  __shared__ float tile[64][65];
  const int br = blockIdx.y * 64, bc = blockIdx.x * 64;
  const int tid = threadIdx.x;
#pragma unroll
  for (int t = 0; t < 16; ++t) {
    int idx = t * 256 + tid;
    int r = idx >> 6, c = idx & 63;
    tile[r][c] = in[(size_t)(br + r) * n + bc + c];
  }
  __syncthreads();
#pragma unroll
  for (int t = 0; t < 16; ++t) {
    int idx = t * 256 + tid;
    int r = idx >> 6, c = idx & 63;
    out[(size_t)(bc + r) * n + br + c] = f2bf(tile[c][r]);
  }
}

// ---- bias_c[n] = 2048 * sum_k bv[k]*Wo[k,n] + bo[n] ------------------------
__global__ __launch_bounds__(256) void bias_fuse(
    const float* __restrict__ bv, const float* __restrict__ Wo,
    const float* __restrict__ bo, float* __restrict__ biasc, int D, int N) {
  __shared__ float red[256];
  const int tid = threadIdx.x;
  const int nx = tid & 15, ky = tid >> 4;
  const int n = blockIdx.x * 16 + nx;
  float s = 0.f;
  for (int k = ky; k < D; k += 16)
    s += bv[k] * Wo[(size_t)k * N + n];
  red[tid] = s;
  __syncthreads();
#pragma unroll
  for (int st = 128; st >= 16; st >>= 1) {
    if (tid < st) red[tid] += red[tid + st];
    __syncthreads();
  }
  if (ky == 0) biasc[n] = 2048.0f * red[nx] + bo[n];
}

// ---- Wt[m,k'] = 2048 * sum_j Wot[m,j] * Wv[k',j]; Wv staged as fp32 --------
// BM=BN=64, BK=64, grid 16x16 (256 blocks = full chip), 4 waves each 32x32.
__global__ __launch_bounds__(256) void gemm_w(
    const short* __restrict__ Wot, const float* __restrict__ Wv,
    short* __restrict__ Wt, int N, int K) {
  constexpr int BK = 64;
  __shared__ __align__(16) short As[64 * BK];   //  8 KB bf16
  __shared__ __align__(16) float Bsf[64 * BK];  // 16 KB fp32
  const int tid = threadIdx.x, lane = tid & 63, wave = tid >> 6;
  const int bm = blockIdx.y * 64, bn = blockIdx.x * 64;
  const int wm = (wave >> 1) * 32, wn = (wave & 1) * 32;
  const int l15 = lane & 15, quad = lane >> 4;

  f32x4 acc[2][2];
#pragma unroll
  for (int i = 0; i < 2; ++i)
#pragma unroll
    for (int j = 0; j < 2; ++j) acc[i][j] = (f32x4){0.f, 0.f, 0.f, 0.f};

  const int ar = tid >> 3, ac8 = (tid & 7) ^ (ar & 7);
  const short* pa = Wot + (size_t)(bm + ar) * K + ac8 * 8;
  short* la = As + tid * 8;
  const int br = tid >> 4, bc4 = (tid & 15) ^ (br & 7);
  const float* pb = Wv + (size_t)(bn + br) * K + bc4 * 4;
  float* lb = Bsf + tid * 4;

  for (int kt = 0; kt < K; kt += BK) {
#pragma unroll
    for (int s = 0; s < 2; ++s) GLD16(pa + (size_t)(32 * s) * K, la + 2048 * s);
#pragma unroll
    for (int s = 0; s < 4; ++s) GLD16(pb + (size_t)(16 * s) * K, lb + 1024 * s);
    pa += BK; pb += BK;
    __syncthreads();
#pragma unroll
    for (int kk = 0; kk < 2; ++kk) {
      bf16x8 af[2], bfr[2];
#pragma unroll
      for (int i = 0; i < 2; ++i) {
        const int r = wm + i * 16 + l15;
        af[i] = *(const bf16x8*)(As + r * BK + ((kk * 4 + quad) ^ (r & 7)) * 8);
      }
#pragma unroll
      for (int j = 0; j < 2; ++j) {
        const int r = wn + j * 16 + l15;
        const int c4 = kk * 8 + quad * 2;
        f32x4 u0 = *(const f32x4*)(Bsf + (r * 16 + (c4 ^ (r & 7))) * 4);
        f32x4 u1 = *(const f32x4*)(Bsf + (r * 16 + ((c4 + 1) ^ (r & 7))) * 4);
        bfr[j] = pack8(u0, u1);
      }
#pragma unroll
      for (int i = 0; i < 2; ++i)
#pragma unroll
        for (int j = 0; j < 2; ++j)
          acc[i][j] = __builtin_amdgcn_mfma_f32_16x16x32_bf16(
              af[i], bfr[j], acc[i][j], 0, 0, 0);
    }
    __syncthreads();
  }
#pragma unroll
  for (int j = 0; j < 2; ++j) {
    const int col = bn + wn + j * 16 + l15;
#pragma unroll
    for (int i = 0; i < 2; ++i) {
      const int row0 = bm + wm + i * 16 + quad * 4;
#pragma unroll
      for (int r = 0; r < 4; ++r)
        Wt[(size_t)(row0 + r) * N + col] = f2bf(2048.f * acc[i][j][r]);
    }
  }
}

// ---- out = x_bf @ Wt^T + bias; bf16 K-loop, 128x64 tile, XCD swizzle -------
// 1-D grid of 1024: bm = b&63 (so b%8 = bm%8 -> all 16 N-tiles of one A-tile
// share an XCD's L2), bn = b>>6. 4 blocks/CU (16 waves) hides K-loop barrier
// drains. 4 waves: wave&1 -> 64-row half, wave>>1 -> 32-col half; each wave
// 4x2 of 16x16x32 MFMA. Epilogue: acc -> LDS (stride-36) -> dwordx4 stores.
__global__ __launch_bounds__(256) void gemm_main(
    const short* __restrict__ A, const short* __restrict__ Bt,
    const float* __restrict__ bias, float* __restrict__ Out,
    int M, int N, int K) {
  constexpr int BK = 64;
  __shared__ __align__(16) char smem[24576];  // As 16K + Bs 8K; epilogue T
  short* As = (short*)smem;
  short* Bs = (short*)(smem + 16384);
  const int tid = threadIdx.x, lane = tid & 63, wave = tid >> 6;
  const int b = blockIdx.x;
  const int bm = (b & 63) * 128;
  const int bn = (b >> 6) * 64;
  const int wm = (wave & 1) * 64, wn = (wave >> 1) * 32;
  const int l15 = lane & 15, quad = lane >> 4;

  f32x4 acc[4][2];
#pragma unroll
  for (int i = 0; i < 4; ++i)
#pragma unroll
    for (int j = 0; j < 2; ++j) acc[i][j] = (f32x4){0.f, 0.f, 0.f, 0.f};

  // staging with XOR chunk swizzle (LDS[row][c8] = global [row][c8^(row&7)])
  const int srow = tid >> 3, sc8 = (tid & 7) ^ (srow & 7);
  const short* pa = A + (size_t)(bm + srow) * K + sc8 * 8;
  const short* pb = Bt + (size_t)(bn + srow) * K + sc8 * 8;
  short* la = As + tid * 8;
  short* lb = Bs + tid * 8;

  for (int kt = 0; kt < K; kt += BK) {
#pragma unroll
    for (int s = 0; s < 4; ++s) GLD16(pa + (size_t)(32 * s) * K, la + 2048 * s);
#pragma unroll
    for (int s = 0; s < 2; ++s) GLD16(pb + (size_t)(32 * s) * K, lb + 2048 * s);
    pa += BK; pb += BK;
    __syncthreads();
#pragma unroll
    for (int kk = 0; kk < 2; ++kk) {
      bf16x8 af[4], bfr[2];
#pragma unroll
      for (int i = 0; i < 4; ++i) {
        const int r = wm + i * 16 + l15;
        af[i] = *(const bf16x8*)(As + r * BK + ((kk * 4 + quad) ^ (r & 7)) * 8);
      }
#pragma unroll
      for (int j = 0; j < 2; ++j) {
        const int r = wn + j * 16 + l15;
        bfr[j] = *(const bf16x8*)(Bs + r * BK + ((kk * 4 + quad) ^ (r & 7)) * 8);
      }
#pragma unroll
      for (int i = 0; i < 4; ++i)
#pragma unroll
        for (int j = 0; j < 2; ++j)
          acc[i][j] = __builtin_amdgcn_mfma_f32_16x16x32_bf16(
              af[i], bfr[j], acc[i][j], 0, 0, 0);
    }
    __syncthreads();
  }

  // epilogue: MFMA C layout (col=l15, row=quad*4+r) -> LDS stride-36 tile ->
  // full-line float4 stores. Per-wave T region; same-wave LDS ordering only.
  float* T = (float*)smem + wave * 576;  // 16 rows x 36 stride
#pragma unroll
  for (int i = 0; i < 4; ++i) {
#pragma unroll
    for (int j = 0; j < 2; ++j) {
      const float bb = bias[bn + wn + j * 16 + l15];
#pragma unroll
      for (int r = 0; r < 4; ++r)
        T[(quad * 4 + r) * 36 + j * 16 + l15] = acc[i][j][r] + bb;
    }
#pragma unroll
    for (int c = 0; c < 2; ++c) {
      const int row = (lane >> 3) + 8 * c;
      f32x4 v = *(const f32x4*)(T + row * 36 + (lane & 7) * 4);
      *(f32x4*)(Out + (size_t)(bm + wm + i * 16 + row) * N + bn + wn +
                (lane & 7) * 4) = v;
    }
  }
}

extern "C" void kernel_launch(void* const* d_in, const int* in_sizes, int n_in,
                              void* d_out, int out_size, void* d_ws,
                              size_t ws_size, hipStream_t stream) {
  // setup_inputs order: x, encoder_x, Wq, bq, Wk, bk, Wv, bv, Wo, bo
  const float* x  = (const float*)d_in[0];
  const float* Wv = (const float*)d_in[6];
  const float* bv = (const float*)d_in[7];
  const float* Wo = (const float*)d_in[8];
  const float* bo = (const float*)d_in[9];
  float* out = (float*)d_out;

  constexpr int L = 2048, D = 1024, NO = 1024;  // NO = H*QKV
  constexpr int M = 4 * L;                      // B*L = 8192

  char* ws = (char*)d_ws;
  short* x_bf   = (short*)(ws);                 // 16 MB: x as bf16
  short* wot_bf = (short*)(ws + (16u << 20));   //  2 MB: Wo^T bf16
  short* wt_bf  = (short*)(ws + (18u << 20));   //  2 MB: 2048*(Wv@Wo)^T bf16
  float* biasc  = (float*)(ws + (20u << 20));   //  4 KB: fused bias

  cast_f32_bf16<<<(M * D / 8) / 256, 256, 0, stream>>>(x, x_bf, M * D / 8);
  transpose_cast<<<dim3(16, 16), 256, 0, stream>>>(Wo, wot_bf, NO);
  bias_fuse<<<NO / 16, 256, 0, stream>>>(bv, Wo, bo, biasc, D, NO);
  gemm_w<<<dim3(16, 16), 256, 0, stream>>>(wot_bf, Wv, wt_bf, NO, D);
  gemm_main<<<(M / 128) * (NO / 64), 256, 0, stream>>>(
      x_bf, wt_bf, biasc, out, M, NO, D);
}

// Round 7
// 180.994 us; speedup vs baseline: 1.0595x; 1.0230x over previous
//
#include <hip/hip_runtime.h>
#include <stdint.h>

// ---------------------------------------------------------------------------
// CrossAttention_43061342110469 — algebraic reduction:
// einsum('bvhd,bhqk->bvhd', v, softmax(scores)) == v * L  (softmax rows sum
// to 1; summed over q gives L=2048). So out = 2048*(x @ Wv @ Wo) + const.
// encoder_x / Wq / bq / Wk / bk do not affect the output.
//
// 3 kernels: prep (cast_x + transpose_cast(Wo) + bias_fuse, block-range
// dispatch — all independent), gemm_w (Wt = 2048*(Wv@Wo)^T, 32x64 tiles so
// 512 blocks = 2/CU to overlap barrier drains), gemm_main (bf16 MFMA,
// 128x64 tiles, XCD-aware order, XOR-swizzled LDS, coalesced epilogue).
// ---------------------------------------------------------------------------

typedef __attribute__((ext_vector_type(8))) short bf16x8;
typedef __attribute__((ext_vector_type(4))) float f32x4;

typedef __attribute__((address_space(1))) void as1_void;
typedef __attribute__((address_space(3))) void as3_void;
#define GLD16(g, s)                                                          \
  __builtin_amdgcn_global_load_lds((as1_void*)(g), (as3_void*)(s), 16, 0, 0)

__device__ __forceinline__ short f2bf(float f) {
  union { float f; uint32_t u; } v; v.f = f;
  uint32_t r = v.u + 0x7FFFu + ((v.u >> 16) & 1u);  // round-to-nearest-even
  return (short)(r >> 16);
}

// pack 8 fp32 -> bf16x8, round-half-up (+0x8000, take high16 via v_perm)
__device__ __forceinline__ bf16x8 pack8(f32x4 a, f32x4 b) {
  union { f32x4 f; uint32_t u[4]; } x, y;
  x.f = a; y.f = b;
#pragma unroll
  for (int t = 0; t < 4; ++t) x.u[t] += 0x8000u;
#pragma unroll
  for (int t = 0; t < 4; ++t) y.u[t] += 0x8000u;
  union { bf16x8 v; uint32_t u[4]; } o;
  o.u[0] = __builtin_amdgcn_perm(x.u[1], x.u[0], 0x07060302);
  o.u[1] = __builtin_amdgcn_perm(x.u[3], x.u[2], 0x07060302);
  o.u[2] = __builtin_amdgcn_perm(y.u[1], y.u[0], 0x07060302);
  o.u[3] = __builtin_amdgcn_perm(y.u[3], y.u[2], 0x07060302);
  return o.v;
}

// ---- prep: blocks [0,4096) cast x; [4096,4352) transpose Wo; [4352,4416)
// fused bias. All three independent; branch is block-uniform. ---------------
__global__ __launch_bounds__(256) void prep(
    const float* __restrict__ x, short* __restrict__ x_bf,
    const float* __restrict__ Wo, short* __restrict__ wot,
    const float* __restrict__ bv, const float* __restrict__ bo,
    float* __restrict__ biasc) {
  constexpr int N = 1024, D = 1024;
  __shared__ union {
    float tile[64][65];
    float red[256];
  } sm;
  const int b = blockIdx.x, tid = threadIdx.x;

  if (b < 4096) {  // ---- cast x: fp32 -> bf16, 8 elems/thread
    const int i = b * 256 + tid;
    const float4* p = (const float4*)x;
    float4 a = p[2 * (size_t)i], c = p[2 * (size_t)i + 1];
    bf16x8 o;
    o[0] = f2bf(a.x); o[1] = f2bf(a.y); o[2] = f2bf(a.z); o[3] = f2bf(a.w);
    o[4] = f2bf(c.x); o[5] = f2bf(c.y); o[6] = f2bf(c.z); o[7] = f2bf(c.w);
    *(bf16x8*)(x_bf + 8 * (size_t)i) = o;
  } else if (b < 4352) {  // ---- transpose-cast Wo (64x64 tiles via LDS)
    const int b2 = b - 4096;
    const int br = (b2 >> 4) * 64, bc = (b2 & 15) * 64;
#pragma unroll
    for (int t = 0; t < 16; ++t) {
      int idx = t * 256 + tid;
      int r = idx >> 6, c = idx & 63;
      sm.tile[r][c] = Wo[(size_t)(br + r) * N + bc + c];
    }
    __syncthreads();
#pragma unroll
    for (int t = 0; t < 16; ++t) {
      int idx = t * 256 + tid;
      int r = idx >> 6, c = idx & 63;
      wot[(size_t)(bc + r) * N + br + c] = f2bf(sm.tile[c][r]);
    }
  } else {  // ---- bias_c[n] = 2048 * sum_k bv[k]*Wo[k,n] + bo[n]
    const int b3 = b - 4352;
    const int nx = tid & 15, ky = tid >> 4;
    const int n = b3 * 16 + nx;
    float s = 0.f;
    for (int k = ky; k < D; k += 16)
      s += bv[k] * Wo[(size_t)k * N + n];
    sm.red[tid] = s;
    __syncthreads();
#pragma unroll
    for (int st = 128; st >= 16; st >>= 1) {
      if (tid < st) sm.red[tid] += sm.red[tid + st];
      __syncthreads();
    }
    if (ky == 0) biasc[n] = 2048.0f * sm.red[nx] + bo[n];
  }
}

// ---- Wt[m,k'] = 2048 * sum_j Wot[m,j] * Wv[k',j]; Wv staged as fp32 --------
// 32x64 tiles, BK=64, grid 16x32 = 512 blocks (2/CU so the per-tile barrier
// drains of co-resident blocks interleave — R6 had 256 blocks = 1/CU with
// latency fully exposed). 4 waves, each 16x32 (1x2 frags of 16x16x32).
__global__ __launch_bounds__(256) void gemm_w(
    const short* __restrict__ Wot, const float* __restrict__ Wv,
    short* __restrict__ Wt, int N, int K) {
  constexpr int BK = 64;
  __shared__ __align__(16) short As[32 * BK];   //  4 KB bf16
  __shared__ __align__(16) float Bsf[64 * BK];  // 16 KB fp32
  const int tid = threadIdx.x, lane = tid & 63, wave = tid >> 6;
  const int bm = blockIdx.y * 32, bn = blockIdx.x * 64;
  const int wm = (wave & 1) * 16, wn = (wave >> 1) * 32;
  const int l15 = lane & 15, quad = lane >> 4;

  f32x4 acc[2];
  acc[0] = (f32x4){0.f, 0.f, 0.f, 0.f};
  acc[1] = (f32x4){0.f, 0.f, 0.f, 0.f};

  // A: 32 rows x 8 chunks(16B) = 256 chunks, 1/thread, XOR swizzle
  const int ar = tid >> 3, ac8 = (tid & 7) ^ (ar & 7);
  const short* pa = Wot + (size_t)(bm + ar) * K + ac8 * 8;
  short* la = As + tid * 8;
  // B (fp32): 64 rows x 16 chunks(16B) = 1024 chunks, 4/thread
  const int br = tid >> 4, bc4 = (tid & 15) ^ (br & 7);
  const float* pb = Wv + (size_t)(bn + br) * K + bc4 * 4;
  float* lb = Bsf + tid * 4;

  for (int kt = 0; kt < K; kt += BK) {
    GLD16(pa, la);
#pragma unroll
    for (int s = 0; s < 4; ++s) GLD16(pb + (size_t)(16 * s) * K, lb + 1024 * s);
    pa += BK; pb += BK;
    __syncthreads();
#pragma unroll
    for (int kk = 0; kk < 2; ++kk) {
      const int r = wm + l15;
      bf16x8 af =
          *(const bf16x8*)(As + r * BK + ((kk * 4 + quad) ^ (r & 7)) * 8);
#pragma unroll
      for (int j = 0; j < 2; ++j) {
        const int rn = wn + j * 16 + l15;
        const int c4 = kk * 8 + quad * 2;
        f32x4 u0 = *(const f32x4*)(Bsf + (rn * 16 + (c4 ^ (rn & 7))) * 4);
        f32x4 u1 = *(const f32x4*)(Bsf + (rn * 16 + ((c4 + 1) ^ (rn & 7))) * 4);
        acc[j] = __builtin_amdgcn_mfma_f32_16x16x32_bf16(af, pack8(u0, u1),
                                                         acc[j], 0, 0, 0);
      }
    }
    __syncthreads();
  }
#pragma unroll
  for (int j = 0; j < 2; ++j) {
    const int col = bn + wn + j * 16 + l15;
    const int row0 = bm + wm + quad * 4;
#pragma unroll
    for (int r = 0; r < 4; ++r)
      Wt[(size_t)(row0 + r) * N + col] = f2bf(2048.f * acc[j][r]);
  }
}

// ---- out = x_bf @ Wt^T + bias; bf16 K-loop, 128x64 tile, XCD swizzle -------
// 1-D grid of 1024: bm = b&63 (b%8 = bm%8 -> all 16 N-tiles of one A-tile
// share an XCD's L2), bn = b>>6. ~4 blocks/CU hides K-loop barrier drains.
// Epilogue: acc -> LDS (stride-36) -> full-line dwordx4 stores.
__global__ __launch_bounds__(256) void gemm_main(
    const short* __restrict__ A, const short* __restrict__ Bt,
    const float* __restrict__ bias, float* __restrict__ Out,
    int M, int N, int K) {
  constexpr int BK = 64;
  __shared__ __align__(16) char smem[24576];  // As 16K + Bs 8K; epilogue T
  short* As = (short*)smem;
  short* Bs = (short*)(smem + 16384);
  const int tid = threadIdx.x, lane = tid & 63, wave = tid >> 6;
  const int b = blockIdx.x;
  const int bm = (b & 63) * 128;
  const int bn = (b >> 6) * 64;
  const int wm = (wave & 1) * 64, wn = (wave >> 1) * 32;
  const int l15 = lane & 15, quad = lane >> 4;

  f32x4 acc[4][2];
#pragma unroll
  for (int i = 0; i < 4; ++i)
#pragma unroll
    for (int j = 0; j < 2; ++j) acc[i][j] = (f32x4){0.f, 0.f, 0.f, 0.f};

  // staging with XOR chunk swizzle (LDS[row][c8] = global [row][c8^(row&7)])
  const int srow = tid >> 3, sc8 = (tid & 7) ^ (srow & 7);
  const short* pa = A + (size_t)(bm + srow) * K + sc8 * 8;
  const short* pb = Bt + (size_t)(bn + srow) * K + sc8 * 8;
  short* la = As + tid * 8;
  short* lb = Bs + tid * 8;

  for (int kt = 0; kt < K; kt += BK) {
#pragma unroll
    for (int s = 0; s < 4; ++s) GLD16(pa + (size_t)(32 * s) * K, la + 2048 * s);
#pragma unroll
    for (int s = 0; s < 2; ++s) GLD16(pb + (size_t)(32 * s) * K, lb + 2048 * s);
    pa += BK; pb += BK;
    __syncthreads();
#pragma unroll
    for (int kk = 0; kk < 2; ++kk) {
      bf16x8 af[4], bfr[2];
#pragma unroll
      for (int i = 0; i < 4; ++i) {
        const int r = wm + i * 16 + l15;
        af[i] = *(const bf16x8*)(As + r * BK + ((kk * 4 + quad) ^ (r & 7)) * 8);
      }
#pragma unroll
      for (int j = 0; j < 2; ++j) {
        const int r = wn + j * 16 + l15;
        bfr[j] = *(const bf16x8*)(Bs + r * BK + ((kk * 4 + quad) ^ (r & 7)) * 8);
      }
#pragma unroll
      for (int i = 0; i < 4; ++i)
#pragma unroll
        for (int j = 0; j < 2; ++j)
          acc[i][j] = __builtin_amdgcn_mfma_f32_16x16x32_bf16(
              af[i], bfr[j], acc[i][j], 0, 0, 0);
    }
    __syncthreads();
  }

  // epilogue: MFMA C layout (col=l15, row=quad*4+r) -> LDS stride-36 tile ->
  // full-line float4 stores. Per-wave T region; same-wave LDS ordering only.
  float* T = (float*)smem + wave * 576;  // 16 rows x 36 stride
#pragma unroll
  for (int i = 0; i < 4; ++i) {
#pragma unroll
    for (int j = 0; j < 2; ++j) {
      const float bb = bias[bn + wn + j * 16 + l15];
#pragma unroll
      for (int r = 0; r < 4; ++r)
        T[(quad * 4 + r) * 36 + j * 16 + l15] = acc[i][j][r] + bb;
    }
#pragma unroll
    for (int c = 0; c < 2; ++c) {
      const int row = (lane >> 3) + 8 * c;
      f32x4 v = *(const f32x4*)(T + row * 36 + (lane & 7) * 4);
      *(f32x4*)(Out + (size_t)(bm + wm + i * 16 + row) * N + bn + wn +
                (lane & 7) * 4) = v;
    }
  }
}

extern "C" void kernel_launch(void* const* d_in, const int* in_sizes, int n_in,
                              void* d_out, int out_size, void* d_ws,
                              size_t ws_size, hipStream_t stream) {
  // setup_inputs order: x, encoder_x, Wq, bq, Wk, bk, Wv, bv, Wo, bo
  const float* x  = (const float*)d_in[0];
  const float* Wv = (const float*)d_in[6];
  const float* bv = (const float*)d_in[7];
  const float* Wo = (const float*)d_in[8];
  const float* bo = (const float*)d_in[9];
  float* out = (float*)d_out;

  constexpr int L = 2048, D = 1024, NO = 1024;  // NO = H*QKV
  constexpr int M = 4 * L;                      // B*L = 8192

  char* ws = (char*)d_ws;
  short* x_bf   = (short*)(ws);                 // 16 MB: x as bf16
  short* wot_bf = (short*)(ws + (16u << 20));   //  2 MB: Wo^T bf16
  short* wt_bf  = (short*)(ws + (18u << 20));   //  2 MB: 2048*(Wv@Wo)^T bf16
  float* biasc  = (float*)(ws + (20u << 20));   //  4 KB: fused bias

  prep<<<4416, 256, 0, stream>>>(x, x_bf, Wo, wot_bf, bv, bo, biasc);
  gemm_w<<<dim3(16, 32), 256, 0, stream>>>(wot_bf, Wv, wt_bf, NO, D);
  gemm_main<<<(M / 128) * (NO / 64), 256, 0, stream>>>(
      x_bf, wt_bf, biasc, out, M, NO, D);
}